// Round 7
// baseline (2793.407 us; speedup 1.0000x reference)
//
#include <hip/hip_runtime.h>
#include <hip/hip_bf16.h>
#include <math.h>

typedef unsigned short u16;
typedef unsigned char u8;
typedef unsigned int u32;
typedef unsigned long long u64;
typedef __attribute__((ext_vector_type(8))) short bf16x8;
typedef __attribute__((ext_vector_type(4))) float f32x4;
typedef __attribute__((ext_vector_type(2))) float f32x2;

__device__ __forceinline__ float b2f(u16 u) {
    union { unsigned int i; float f; } v; v.i = ((unsigned int)u) << 16; return v.f;
}
__device__ __forceinline__ u16 f2b(float f) {
    unsigned int i = __float_as_uint(f);
    unsigned int r = (i + 0x7FFFu + ((i >> 16) & 1u)) >> 16;
    return (u16)r;
}
// fp8 e4m3 HW conversions (gfx950 OCP)
__device__ __forceinline__ f32x2 fp8x2_lo(u32 w) { return __builtin_amdgcn_cvt_pk_f32_fp8((int)w, false); }
__device__ __forceinline__ f32x2 fp8x2_hi(u32 w) { return __builtin_amdgcn_cvt_pk_f32_fp8((int)w, true); }
__device__ __forceinline__ u32 f32x2_to_fp8(float a, float b) {
    return (u32)__builtin_amdgcn_cvt_pk_fp8_f32(a, b, 0, false);
}

#define BSHIFT 8            // 256 nodes per bucket
#define NPB 256             // nodes per bucket
#define EPB 4096            // edges per bucketA block
#define BH_CHUNK 16384      // edges per bhist block
#define SRC_MASK 0x1FFFFu   // 17 bits (N < 131072)

// ---------------- bucket histogram (up to 512 buckets) ----------------
__global__ __launch_bounds__(256) void k_bhist(const int* __restrict__ dst, int E,
                                               int* __restrict__ bcnt, int nbuck) {
    __shared__ int h[512];
    int t = threadIdx.x;
    h[t] = 0; h[t + 256] = 0;
    __syncthreads();
    int e0 = blockIdx.x * BH_CHUNK;
    int e1 = e0 + BH_CHUNK; if (e1 > E) e1 = E;
    for (int i = e0 + t; i < e1; i += 256) atomicAdd(&h[dst[i] >> BSHIFT], 1);
    __syncthreads();
    for (int i = t; i < 512; i += 256)
        if (i < nbuck && h[i] > 0) atomicAdd(&bcnt[i], h[i]);
}

// ---------------- bucket base scan (exclusive, up to 512 entries) ------------
__global__ __launch_bounds__(256) void k_bscan(const int* __restrict__ bcnt,
                                               int* __restrict__ bbase,
                                               int nbuck, int E) {
    __shared__ int lds[512];
    int t = threadIdx.x;
    int m0 = (t < nbuck) ? bcnt[t] : 0;
    int m1 = (t + 256 < nbuck) ? bcnt[t + 256] : 0;
    lds[t] = m0; lds[t + 256] = m1;
    __syncthreads();
    for (int s = 1; s < 512; s <<= 1) {
        int v0 = (t >= s) ? lds[t - s] : 0;
        int i1 = t + 256;
        int v1 = (i1 >= s) ? lds[i1 - s] : 0;
        __syncthreads();
        lds[t] += v0;
        lds[i1] += v1;
        __syncthreads();
    }
    if (t < nbuck) bbase[t] = lds[t] - m0;
    if (t + 256 < nbuck) bbase[t + 256] = lds[t + 256] - m1;
    if (t == 0) bbase[nbuck] = E;
}

// ---------------- bucketA: stage edges grouped by dst-bucket ----------------
__global__ __launch_bounds__(256) void k_bucketA(const int* __restrict__ src,
                                                 const int* __restrict__ dst, int E,
                                                 const int* __restrict__ bbase,
                                                 int* __restrict__ bkcur,
                                                 u32* __restrict__ stage, int nbuck) {
    __shared__ int cntL[512];
    __shared__ int prefE[512];
    __shared__ int allocL[512];
    __shared__ int baseL[512];
    __shared__ u64 stageL[EPB];
    int t = threadIdx.x;
    int e0 = blockIdx.x * EPB;

    for (int i = t; i < 512; i += 256) cntL[i] = 0;
    __syncthreads();
#pragma unroll
    for (int j = 0; j < EPB / 256; j++) {
        int e = e0 + j * 256 + t;
        if (e < E) atomicAdd(&cntL[dst[e] >> BSHIFT], 1);
    }
    __syncthreads();
    for (int i = t; i < 512; i += 256) prefE[i] = cntL[i];
    __syncthreads();
    for (int s = 1; s < 512; s <<= 1) {
        int v0 = (t >= s) ? prefE[t - s] : 0;
        int i1 = t + 256;
        int v1 = (i1 >= s) ? prefE[i1 - s] : 0;
        __syncthreads();
        prefE[t] += v0;
        prefE[i1] += v1;
        __syncthreads();
    }
    for (int i = t; i < 512; i += 256) {
        int ex = prefE[i] - cntL[i];
        prefE[i] = ex;
        allocL[i] = ex;
    }
    __syncthreads();
    for (int i = t; i < 512; i += 256) {
        if (i < nbuck && cntL[i] > 0)
            baseL[i] = bbase[i] + atomicAdd(&bkcur[i], cntL[i]);
    }
    __syncthreads();
#pragma unroll
    for (int j = 0; j < EPB / 256; j++) {
        int e = e0 + j * 256 + t;
        if (e < E) {
            int d = dst[e];
            int b = d >> BSHIFT;
            int slot = atomicAdd(&allocL[b], 1);
            stageL[slot] = ((u64)(unsigned)d << 32) | (unsigned)src[e];
        }
    }
    __syncthreads();
    int tot = E - e0; if (tot > EPB) tot = EPB;
    for (int i = t; i < tot; i += 256) {
        u64 v = stageL[i];
        int b = (int)(v >> (32 + BSHIFT));
        u32 dl = (u32)((v >> 32) & (u32)(NPB - 1));
        u32 packed = (dl << 17) | ((u32)v & SRC_MASK);
        stage[baseL[b] + (i - prefE[b])] = packed;
    }
}

// ------- dinv from staged edges: bucket-local histogram -------
__global__ __launch_bounds__(256) void k_dinvB(const u32* __restrict__ stage,
                                               const int* __restrict__ bbase,
                                               float* __restrict__ dinv, int N) {
    __shared__ int hist[NPB];
    int b = blockIdx.x, t = threadIdx.x;
    if (t < NPB) hist[t] = 0;
    __syncthreads();
    int rbeg = bbase[b], rend = bbase[b + 1];
    for (int i = rbeg + t; i < rend; i += 256) atomicAdd(&hist[stage[i] >> 17], 1);
    __syncthreads();
    int node = (b << BSHIFT) + t;
    if (t < NPB && node < N) dinv[node] = rsqrtf((float)(hist[t] + 1));  // +1 self loop
}

// ---------------- W transpose+bf16 prep ----------------
__global__ void k_wt(const float* __restrict__ W1, const float* __restrict__ W2,
                     u16* __restrict__ Wt1, u16* __restrict__ Wt2) {
    const float* W = blockIdx.x ? W2 : W1;
    u16* Wt = blockIdx.x ? Wt2 : Wt1;
    int t = threadIdx.x;
    for (int i = t; i < 16384; i += 256) {
        int k = i >> 7, c = i & 127;
        Wt[c * 128 + k] = f2b(W[i]);
    }
}

// -------- MFMA GEMM: Z[N,128](fp8) = dinv[r] * (X[N,128] @ W) ----------------
template <typename TIN>
__global__ __launch_bounds__(256) void k_gemm_mfma(const TIN* __restrict__ X,
                                                   const u16* __restrict__ Wt,
                                                   const float* __restrict__ dinv,
                                                   u8* __restrict__ Y, int N) {
    __shared__ u16 WtL[128 * 128];
    __shared__ u8 YL[4][16 * 128];
    int t = threadIdx.x;
    {
        const char* gsrc = (const char*)Wt;
        char* lbase = (char*)WtL;
#pragma unroll
        for (int i = 0; i < 8; i++) {
            int byte = (i * 256 + t) * 16;
            int row = byte >> 8;
            int swz = byte ^ ((row & 7) << 4);
            *(uint4*)(lbase + swz) = *(const uint4*)(gsrc + byte);
        }
    }
    __syncthreads();

    int wave = t >> 6, lane = t & 63;
    int r0w = blockIdx.x * 64 + wave * 16;
    int lrow = lane & 15, lseg = lane >> 4;

    bf16x8 a[4];
    {
        int row = r0w + lrow; if (row >= N) row = N - 1;
        if constexpr (sizeof(TIN) == 4) {
            const float* xp = (const float*)X + (size_t)row * 128 + lseg * 8;
#pragma unroll
            for (int j = 0; j < 4; j++) {
                float4 f0 = *(const float4*)(xp + j * 32);
                float4 f1 = *(const float4*)(xp + j * 32 + 4);
                bf16x8 v;
                v[0] = (short)f2b(f0.x); v[1] = (short)f2b(f0.y);
                v[2] = (short)f2b(f0.z); v[3] = (short)f2b(f0.w);
                v[4] = (short)f2b(f1.x); v[5] = (short)f2b(f1.y);
                v[6] = (short)f2b(f1.z); v[7] = (short)f2b(f1.w);
                a[j] = v;
            }
        } else {
            const u16* xp = (const u16*)X + (size_t)row * 128 + lseg * 8;
#pragma unroll
            for (int j = 0; j < 4; j++) a[j] = *(const bf16x8*)(xp + j * 32);
        }
    }

    f32x4 acc[8];
#pragma unroll
    for (int c = 0; c < 8; c++) acc[c] = (f32x4){0.f, 0.f, 0.f, 0.f};

    const char* lbase = (const char*)WtL;
#pragma unroll
    for (int c = 0; c < 8; c++) {
        int wrow = c * 16 + lrow;
#pragma unroll
        for (int j = 0; j < 4; j++) {
            int byte = wrow * 256 + (j * 32 + lseg * 8) * 2;
            int swz = byte ^ ((wrow & 7) << 4);
            bf16x8 bf = *(const bf16x8*)(lbase + swz);
            acc[c] = __builtin_amdgcn_mfma_f32_16x16x32_bf16(a[j], bf, acc[c], 0, 0, 0);
        }
    }

    float dv[4];
    int rowb = r0w + lseg * 4;
#pragma unroll
    for (int r = 0; r < 4; r++) {
        int row = rowb + r;
        dv[r] = (row < N) ? dinv[row] : 0.f;
    }
    u8* yw = &YL[wave][0];
#pragma unroll
    for (int c = 0; c < 8; c++) {
        u32 p01 = f32x2_to_fp8(acc[c][0] * dv[0], acc[c][1] * dv[1]);
        u32 p23 = f32x2_to_fp8(acc[c][2] * dv[2], acc[c][3] * dv[3]);
        int base = (lseg * 4) * 128 + c * 16 + lrow;
        yw[base]           = (u8)p01;
        yw[base + 128]     = (u8)(p01 >> 8);
        yw[base + 256]     = (u8)p23;
        yw[base + 384]     = (u8)(p23 >> 8);
    }
#pragma unroll
    for (int k = 0; k < 2; k++) {
        int idx = lane + 64 * k;
        int row = idx >> 3;
        int seg = idx & 7;
        int grow = r0w + row;
        uint4 v = *(const uint4*)&yw[row * 128 + seg * 16];
        if (grow < N) *(uint4*)&Y[(size_t)grow * 128 + seg * 16] = v;
    }
}

// -------- fused aggregation: bucket-local LDS accumulate from staged edges ---
// grid = (nbuck, 2 slices of 64 feats). LDS acc: 256 nodes x 64 f32 (64 KB),
// XOR-swizzled (f ^ (ln&31)) for bank spread. 8 lanes/edge x 8B = one 64B req.
__device__ __forceinline__ void acc8(float* __restrict__ a, int ln, int fo, uint2 d) {
    int x = ln & 31;
    f32x2 f;
    f = fp8x2_lo(d.x); atomicAdd(&a[(fo + 0) ^ x], f.x); atomicAdd(&a[(fo + 1) ^ x], f.y);
    f = fp8x2_hi(d.x); atomicAdd(&a[(fo + 2) ^ x], f.x); atomicAdd(&a[(fo + 3) ^ x], f.y);
    f = fp8x2_lo(d.y); atomicAdd(&a[(fo + 4) ^ x], f.x); atomicAdd(&a[(fo + 5) ^ x], f.y);
    f = fp8x2_hi(d.y); atomicAdd(&a[(fo + 6) ^ x], f.x); atomicAdd(&a[(fo + 7) ^ x], f.y);
}

template <int DO_RELU, int DO_POOL>
__global__ __launch_bounds__(512) void k_aggB(const u8* __restrict__ Z,
                                              const float* __restrict__ dinv,
                                              const int* __restrict__ bbase,
                                              const u32* __restrict__ stage,
                                              const float* __restrict__ bias,
                                              u16* __restrict__ H,
                                              const int* __restrict__ batch,
                                              float* __restrict__ pooled, int N) {
    __shared__ float accL[NPB * 64];
    int t = threadIdx.x;
    int b = blockIdx.x;
    int FB = blockIdx.y * 64;
    int node_lo = b << BSHIFT;

    for (int i = t; i < NPB * 64; i += 512) accL[i] = 0.f;
    __syncthreads();

    int rbeg = bbase[b], rend = bbase[b + 1];
    int sub = t & 7;           // 8 lanes per edge
    int fo = sub * 8;          // feature offset within slice
    int eslot = t >> 3;        // 0..63

    for (int e0 = rbeg + eslot; e0 < rend; e0 += 128) {
        int e1 = e0 + 64;
        bool has1 = e1 < rend;
        u32 v0 = stage[e0];
        u32 v1 = has1 ? stage[e1] : 0;
        uint2 d0 = *(const uint2*)&Z[(size_t)(v0 & SRC_MASK) * 128 + FB + fo];
        uint2 d1 = make_uint2(0, 0);
        if (has1) d1 = *(const uint2*)&Z[(size_t)(v1 & SRC_MASK) * 128 + FB + fo];
        int l0 = (int)(v0 >> 17);
        acc8(&accL[l0 * 64], l0, fo, d0);
        if (has1) {
            int l1 = (int)(v1 >> 17);
            acc8(&accL[l1 * 64], l1, fo, d1);
        }
    }
    __syncthreads();

    // epilogue: self-loop + dinv scale + bias (+relu), write H bf16
    float bb[8];
#pragma unroll
    for (int j = 0; j < 8; j++) bb[j] = bias[FB + fo + j];
#pragma unroll
    for (int pass = 0; pass < 4; ++pass) {
        int ln = eslot + pass * 64;
        int node = node_lo + ln;
        float* a = &accL[ln * 64];
        int x = ln & 31;
        if (node < N) {
            uint2 dz = *(const uint2*)&Z[(size_t)node * 128 + FB + fo];
            float dn = dinv[node];
            f32x2 f0 = fp8x2_lo(dz.x), f1 = fp8x2_hi(dz.x);
            f32x2 f2 = fp8x2_lo(dz.y), f3 = fp8x2_hi(dz.y);
            float z[8] = {f0.x, f0.y, f1.x, f1.y, f2.x, f2.y, f3.x, f3.y};
            float h[8];
#pragma unroll
            for (int j = 0; j < 8; j++) {
                float v = dn * (a[(fo + j) ^ x] + z[j]) + bb[j];
                if (DO_RELU) v = fmaxf(v, 0.f);
                h[j] = v;
            }
            u16 ob[8];
#pragma unroll
            for (int j = 0; j < 8; j++) ob[j] = f2b(h[j]);
            *(uint4*)&H[(size_t)node * 128 + FB + fo] = *(uint4*)ob;
            if (DO_POOL) {
#pragma unroll
                for (int j = 0; j < 8; j++) a[(fo + j) ^ x] = h[j];
            }
        } else if (DO_POOL) {
#pragma unroll
            for (int j = 0; j < 8; j++) a[(fo + j) ^ x] = 0.f;
        }
    }

    if (DO_POOL) {
        __syncthreads();
        // per-thread: one feature, 32-node chunk; flush at graph boundaries
        int f = t & 63;
        int c = t >> 6;        // 0..7
        int ln0 = c * 32;
        float acc = 0.f;
        int g = -1;
        for (int i = 0; i < 32; ++i) {
            int ln = ln0 + i;
            int node = node_lo + ln;
            if (node >= N) break;
            int gn = batch[node];
            if (gn != g) {
                if (g >= 0) atomicAdd(&pooled[g * 128 + FB + f], acc);
                acc = 0.f; g = gn;
            }
            acc += accL[ln * 64 + (f ^ (ln & 31))];
        }
        if (g >= 0) atomicAdd(&pooled[g * 128 + FB + f], acc);
    }
}

// ---------------- pool finalize ----------------
__global__ void k_pool_final(const int* __restrict__ batch, int N,
                             float* __restrict__ pooled) {
    int g = blockIdx.x;
    int t = threadIdx.x;
    __shared__ int sh[2];
    if (t == 0) {
        int lo = 0, hi = N;
        while (lo < hi) { int m = (lo + hi) >> 1; if (batch[m] < g) lo = m + 1; else hi = m; }
        sh[0] = lo;
        lo = 0; hi = N;
        while (lo < hi) { int m = (lo + hi) >> 1; if (batch[m] < g + 1) lo = m + 1; else hi = m; }
        sh[1] = lo;
    }
    __syncthreads();
    float cnt = (float)(sh[1] - sh[0]);
    if (cnt < 1.f) cnt = 1.f;
    pooled[g * 128 + t] /= cnt;
}

// ---------------- final MLP ----------------
__global__ void k_mlp(const float* __restrict__ pooled, const float* __restrict__ Wl1,
                      const float* __restrict__ bl1, const float* __restrict__ Wl2,
                      const float* __restrict__ bl2, float* __restrict__ out) {
    int g = blockIdx.x;
    int j = threadIdx.x;
    float acc = 0.f;
#pragma unroll 8
    for (int k = 0; k < 128; k++) acc += pooled[g * 128 + k] * Wl1[k * 64 + j];
    float h = fmaxf(acc + bl1[j], 0.f);
    float v = h * Wl2[j];
#pragma unroll
    for (int off = 32; off > 0; off >>= 1) v += __shfl_down(v, off);
    if (j == 0) out[g] = 1.f / (1.f + expf(-(v + bl2[0])));
}

// ---------------- launch ----------------
extern "C" void kernel_launch(void* const* d_in, const int* in_sizes, int n_in,
                              void* d_out, int out_size, void* d_ws, size_t ws_size,
                              hipStream_t stream) {
    const float* x    = (const float*)d_in[0];
    const int*   edge = (const int*)d_in[1];
    const int*   batch= (const int*)d_in[2];
    const float* W1   = (const float*)d_in[3];
    const float* b1   = (const float*)d_in[4];
    const float* W2   = (const float*)d_in[5];
    const float* b2   = (const float*)d_in[6];
    const float* Wl1  = (const float*)d_in[7];
    const float* bl1  = (const float*)d_in[8];
    const float* Wl2  = (const float*)d_in[9];
    const float* bl2  = (const float*)d_in[10];
    float* out = (float*)d_out;

    int N = in_sizes[0] / 128;
    int E = in_sizes[1] / 2;
    const int* src = edge;
    const int* dst = edge + E;
    int nbuck = (N + NPB - 1) >> BSHIFT;

    char* ws = (char*)d_ws;
    size_t off = 0;
    auto alloc = [&](size_t bytes) { void* p = ws + off; off += (bytes + 511) & ~(size_t)511; return p; };
    float* dinv    = (float*)alloc((size_t)N * 4);
    u8*    Z       = (u8*)alloc((size_t)N * 128);        // fp8 gather buffer
    u16*   H       = (u16*)alloc((size_t)N * 128 * 2);   // bf16 layer output
    u32*   stage   = (u32*)alloc((size_t)E * 4);
    int*   bcnt    = (int*)alloc(512 * 4);
    int*   bbase   = (int*)alloc(516 * 4);
    int*   bkcur   = (int*)alloc(512 * 4);
    float* pooled  = (float*)alloc(64 * 128 * 4);
    u16*   Wt1     = (u16*)alloc(128 * 128 * 2);
    u16*   Wt2     = (u16*)alloc(128 * 128 * 2);

    hipMemsetAsync(bcnt, 0, 512 * 4, stream);
    hipMemsetAsync(bkcur, 0, 512 * 4, stream);
    hipMemsetAsync(pooled, 0, 64 * 128 * 4, stream);

    k_bhist<<<(E + BH_CHUNK - 1) / BH_CHUNK, 256, 0, stream>>>(dst, E, bcnt, nbuck);
    k_bscan<<<1, 256, 0, stream>>>(bcnt, bbase, nbuck, E);
    k_wt<<<2, 256, 0, stream>>>(W1, W2, Wt1, Wt2);
    k_bucketA<<<(E + EPB - 1) / EPB, 256, 0, stream>>>(src, dst, E, bbase, bkcur, stage, nbuck);
    k_dinvB<<<nbuck, 256, 0, stream>>>(stage, bbase, dinv, N);

    k_gemm_mfma<float><<<(N + 63) / 64, 256, 0, stream>>>(x, Wt1, dinv, Z, N);
    k_aggB<1, 0><<<dim3(nbuck, 2), 512, 0, stream>>>(Z, dinv, bbase, stage, b1, H, batch, pooled, N);
    k_gemm_mfma<u16><<<(N + 63) / 64, 256, 0, stream>>>(H, Wt2, dinv, Z, N);
    k_aggB<0, 1><<<dim3(nbuck, 2), 512, 0, stream>>>(Z, dinv, bbase, stage, b2, H, batch, pooled, N);
    k_pool_final<<<64, 128, 0, stream>>>(batch, N, pooled);
    k_mlp<<<64, 64, 0, stream>>>(pooled, Wl1, bl1, Wl2, bl2, out);
}

// Round 8
// 279.073 us; speedup vs baseline: 10.0096x; 10.0096x over previous
//
#include <hip/hip_runtime.h>
#include <hip/hip_bf16.h>
#include <math.h>

typedef unsigned short u16;
typedef unsigned char u8;
typedef unsigned int u32;
typedef unsigned long long u64;
typedef __attribute__((ext_vector_type(8))) short bf16x8;
typedef __attribute__((ext_vector_type(4))) float f32x4;
typedef __attribute__((ext_vector_type(2))) float f32x2;

__device__ __forceinline__ float b2f(u16 u) {
    union { unsigned int i; float f; } v; v.i = ((unsigned int)u) << 16; return v.f;
}
__device__ __forceinline__ u16 f2b(float f) {
    unsigned int i = __float_as_uint(f);
    unsigned int r = (i + 0x7FFFu + ((i >> 16) & 1u)) >> 16;
    return (u16)r;
}
// fp8 e4m3 HW conversions (gfx950 OCP)
__device__ __forceinline__ f32x2 fp8x2_lo(u32 w) { return __builtin_amdgcn_cvt_pk_f32_fp8((int)w, false); }
__device__ __forceinline__ f32x2 fp8x2_hi(u32 w) { return __builtin_amdgcn_cvt_pk_f32_fp8((int)w, true); }
__device__ __forceinline__ u32 f32x2_to_fp8(float a, float b) {
    return (u32)__builtin_amdgcn_cvt_pk_fp8_f32(a, b, 0, false);
}

#define BSHIFT 9            // 512 nodes per bucket
#define EPB 4096            // edges per bucketA block
#define BH_CHUNK 16384      // edges per bhist block
#define SRC_MASK 0x1FFFFu   // 17 bits (N < 131072)

// ---------------- bucket histogram ----------------
__global__ __launch_bounds__(256) void k_bhist(const int* __restrict__ dst, int E,
                                               int* __restrict__ bcnt, int nbuck) {
    __shared__ int h[256];
    int t = threadIdx.x;
    h[t] = 0;
    __syncthreads();
    int e0 = blockIdx.x * BH_CHUNK;
    int e1 = e0 + BH_CHUNK; if (e1 > E) e1 = E;
    for (int i = e0 + t; i < e1; i += 256) atomicAdd(&h[dst[i] >> BSHIFT], 1);
    __syncthreads();
    if (t < nbuck && h[t] > 0) atomicAdd(&bcnt[t], h[t]);
}

// ---------------- bucket base scan ----------------
__global__ __launch_bounds__(256) void k_bscan(const int* __restrict__ bcnt,
                                               int* __restrict__ bbase,
                                               int* __restrict__ row_off,
                                               int nbuck, int N, int E) {
    __shared__ int lds[256];
    int t = threadIdx.x;
    int mine = (t < nbuck) ? bcnt[t] : 0;
    lds[t] = mine;
    __syncthreads();
    int val = mine;
    for (int s = 1; s < 256; s <<= 1) {
        int add = (t >= s) ? lds[t - s] : 0;
        __syncthreads();
        val += add;
        lds[t] = val;
        __syncthreads();
    }
    if (t < nbuck) bbase[t] = val - mine;
    if (t == nbuck - 1) bbase[nbuck] = val;
    if (t == 0) row_off[N] = E;
}

// ---------------- bucketA: stage edges grouped by dst-bucket ----------------
__global__ __launch_bounds__(256) void k_bucketA(const int* __restrict__ src,
                                                 const int* __restrict__ dst, int E,
                                                 const int* __restrict__ bbase,
                                                 int* __restrict__ bkcur,
                                                 u32* __restrict__ stage, int nbuck) {
    __shared__ int cntL[512];
    __shared__ int prefE[512];
    __shared__ int allocL[512];
    __shared__ int baseL[512];
    __shared__ u64 stageL[EPB];
    int t = threadIdx.x;
    int e0 = blockIdx.x * EPB;

    for (int i = t; i < 512; i += 256) cntL[i] = 0;
    __syncthreads();
#pragma unroll
    for (int j = 0; j < EPB / 256; j++) {
        int e = e0 + j * 256 + t;
        if (e < E) atomicAdd(&cntL[dst[e] >> BSHIFT], 1);
    }
    __syncthreads();
    for (int i = t; i < 512; i += 256) prefE[i] = cntL[i];
    __syncthreads();
    for (int s = 1; s < 512; s <<= 1) {
        int v0 = (t >= s) ? prefE[t - s] : 0;
        int i1 = t + 256;
        int v1 = (i1 >= s) ? prefE[i1 - s] : 0;
        __syncthreads();
        prefE[t] += v0;
        prefE[i1] += v1;
        __syncthreads();
    }
    for (int i = t; i < 512; i += 256) {
        int ex = prefE[i] - cntL[i];
        prefE[i] = ex;
        allocL[i] = ex;
    }
    __syncthreads();
    for (int i = t; i < 512; i += 256) {
        if (i < nbuck && cntL[i] > 0)
            baseL[i] = bbase[i] + atomicAdd(&bkcur[i], cntL[i]);
    }
    __syncthreads();
#pragma unroll
    for (int j = 0; j < EPB / 256; j++) {
        int e = e0 + j * 256 + t;
        if (e < E) {
            int d = dst[e];
            int b = d >> BSHIFT;
            int slot = atomicAdd(&allocL[b], 1);
            stageL[slot] = ((u64)(unsigned)d << 32) | (unsigned)src[e];
        }
    }
    __syncthreads();
    int tot = E - e0; if (tot > EPB) tot = EPB;
    for (int i = t; i < tot; i += 256) {
        u64 v = stageL[i];
        int b = (int)(v >> (32 + BSHIFT));
        u32 d9 = (u32)((v >> 32) & 511u);
        u32 packed = (d9 << 17) | ((u32)v & SRC_MASK);
        stage[baseL[b] + (i - prefE[b])] = packed;
    }
}

// ------- bucketB: local hist+scan -> row_off, dinv, csr placement -------
__global__ __launch_bounds__(256) void k_bucketB(const u32* __restrict__ stage,
                                                 const int* __restrict__ bbase,
                                                 int* __restrict__ csr_src,
                                                 int* __restrict__ row_off,
                                                 float* __restrict__ dinv, int N) {
    __shared__ int hist[512];
    __shared__ int pref[512];
    __shared__ int cur[512];
    int b = blockIdx.x, t = threadIdx.x;
    int node_lo = b << BSHIFT;
    int nloc = N - node_lo; if (nloc > 512) nloc = 512;
    int rbeg = bbase[b], rend = bbase[b + 1];

    for (int i = t; i < 512; i += 256) hist[i] = 0;
    __syncthreads();
    for (int i = rbeg + t; i < rend; i += 256) atomicAdd(&hist[stage[i] >> 17], 1);
    __syncthreads();
    for (int i = t; i < 512; i += 256) pref[i] = hist[i];
    __syncthreads();
    for (int s = 1; s < 512; s <<= 1) {
        int v0 = (t >= s) ? pref[t - s] : 0;
        int i1 = t + 256;
        int v1 = (i1 >= s) ? pref[i1 - s] : 0;
        __syncthreads();
        pref[t] += v0;
        pref[i1] += v1;
        __syncthreads();
    }
    for (int i = t; i < 512; i += 256) {
        int ex = pref[i] - hist[i];
        cur[i] = rbeg + ex;
        if (i < nloc) {
            row_off[node_lo + i] = rbeg + ex;
            dinv[node_lo + i] = rsqrtf((float)(hist[i] + 1));  // +1 self loop
        }
    }
    __syncthreads();
    for (int i = rbeg + t; i < rend; i += 256) {
        u32 v = stage[i];
        int pos = atomicAdd(&cur[v >> 17], 1);
        csr_src[pos] = (int)(v & SRC_MASK);
    }
}

// ---------------- W transpose+bf16 prep ----------------
__global__ void k_wt(const float* __restrict__ W1, const float* __restrict__ W2,
                     u16* __restrict__ Wt1, u16* __restrict__ Wt2) {
    const float* W = blockIdx.x ? W2 : W1;
    u16* Wt = blockIdx.x ? Wt2 : Wt1;
    int t = threadIdx.x;
    for (int i = t; i < 16384; i += 256) {
        int k = i >> 7, c = i & 127;
        Wt[c * 128 + k] = f2b(W[i]);
    }
}

// -------- MFMA GEMM: Z[N,128](fp8) = dinv[r] * (X[N,128] @ W) ----------------
template <typename TIN>
__global__ __launch_bounds__(256) void k_gemm_mfma(const TIN* __restrict__ X,
                                                   const u16* __restrict__ Wt,
                                                   const float* __restrict__ dinv,
                                                   u8* __restrict__ Y, int N) {
    __shared__ u16 WtL[128 * 128];
    __shared__ u8 YL[4][16 * 128];
    int t = threadIdx.x;
    {
        const char* gsrc = (const char*)Wt;
        char* lbase = (char*)WtL;
#pragma unroll
        for (int i = 0; i < 8; i++) {
            int byte = (i * 256 + t) * 16;
            int row = byte >> 8;
            int swz = byte ^ ((row & 7) << 4);
            *(uint4*)(lbase + swz) = *(const uint4*)(gsrc + byte);
        }
    }
    __syncthreads();

    int wave = t >> 6, lane = t & 63;
    int r0w = blockIdx.x * 64 + wave * 16;
    int lrow = lane & 15, lseg = lane >> 4;

    bf16x8 a[4];
    {
        int row = r0w + lrow; if (row >= N) row = N - 1;
        if constexpr (sizeof(TIN) == 4) {
            const float* xp = (const float*)X + (size_t)row * 128 + lseg * 8;
#pragma unroll
            for (int j = 0; j < 4; j++) {
                float4 f0 = *(const float4*)(xp + j * 32);
                float4 f1 = *(const float4*)(xp + j * 32 + 4);
                bf16x8 v;
                v[0] = (short)f2b(f0.x); v[1] = (short)f2b(f0.y);
                v[2] = (short)f2b(f0.z); v[3] = (short)f2b(f0.w);
                v[4] = (short)f2b(f1.x); v[5] = (short)f2b(f1.y);
                v[6] = (short)f2b(f1.z); v[7] = (short)f2b(f1.w);
                a[j] = v;
            }
        } else {
            const u16* xp = (const u16*)X + (size_t)row * 128 + lseg * 8;
#pragma unroll
            for (int j = 0; j < 4; j++) a[j] = *(const bf16x8*)(xp + j * 32);
        }
    }

    f32x4 acc[8];
#pragma unroll
    for (int c = 0; c < 8; c++) acc[c] = (f32x4){0.f, 0.f, 0.f, 0.f};

    const char* lbase = (const char*)WtL;
#pragma unroll
    for (int c = 0; c < 8; c++) {
        int wrow = c * 16 + lrow;
#pragma unroll
        for (int j = 0; j < 4; j++) {
            int byte = wrow * 256 + (j * 32 + lseg * 8) * 2;
            int swz = byte ^ ((wrow & 7) << 4);
            bf16x8 bf = *(const bf16x8*)(lbase + swz);
            acc[c] = __builtin_amdgcn_mfma_f32_16x16x32_bf16(a[j], bf, acc[c], 0, 0, 0);
        }
    }

    float dv[4];
    int rowb = r0w + lseg * 4;
#pragma unroll
    for (int r = 0; r < 4; r++) {
        int row = rowb + r;
        dv[r] = (row < N) ? dinv[row] : 0.f;
    }
    u8* yw = &YL[wave][0];
#pragma unroll
    for (int c = 0; c < 8; c++) {
        u32 p01 = f32x2_to_fp8(acc[c][0] * dv[0], acc[c][1] * dv[1]);
        u32 p23 = f32x2_to_fp8(acc[c][2] * dv[2], acc[c][3] * dv[3]);
        int base = (lseg * 4) * 128 + c * 16 + lrow;
        yw[base]           = (u8)p01;
        yw[base + 128]     = (u8)(p01 >> 8);
        yw[base + 256]     = (u8)p23;
        yw[base + 384]     = (u8)(p23 >> 8);
    }
#pragma unroll
    for (int k = 0; k < 2; k++) {
        int idx = lane + 64 * k;
        int row = idx >> 3;
        int seg = idx & 7;
        int grow = r0w + row;
        uint4 v = *(const uint4*)&yw[row * 128 + seg * 16];
        if (grow < N) *(uint4*)&Y[(size_t)grow * 128 + seg * 16] = v;
    }
}

// -------- aggregation: quad-gather, 16 edges in flight per wave --------------
// 16-lane groups: group g handles edges e+g, e+4+g, e+8+g, e+12+g; each lane
// loads 8 B (8 fp8 feats). Butterfly shfl_xor(16,32) combines the 4 groups.
__global__ __launch_bounds__(256) void k_agg(const u8* __restrict__ Z,
                                             const float* __restrict__ dinv,
                                             const int* __restrict__ row_off,
                                             const int* __restrict__ csr_src,
                                             const float* __restrict__ bias,
                                             u16* __restrict__ OUT, int N, int do_relu) {
    int wave = (blockIdx.x * blockDim.x + threadIdx.x) >> 6;
    int lane = threadIdx.x & 63;
    if (wave >= N) return;
    int g = lane >> 4;          // edge subgroup 0..3
    int fb = (lane & 15) * 8;   // feature base: 8 features per lane
    int beg = row_off[wave], end = row_off[wave + 1];

    float acc[8];
#pragma unroll
    for (int j = 0; j < 8; j++) acc[j] = 0.f;

    // self loop: group 0 only (Z already prescaled by dinv)
    if (g == 0) {
        uint2 v = *(const uint2*)&Z[(size_t)wave * 128 + fb];
        f32x2 f0 = fp8x2_lo(v.x), f1 = fp8x2_hi(v.x);
        f32x2 f2 = fp8x2_lo(v.y), f3 = fp8x2_hi(v.y);
        acc[0] += f0.x; acc[1] += f0.y; acc[2] += f1.x; acc[3] += f1.y;
        acc[4] += f2.x; acc[5] += f2.y; acc[6] += f3.x; acc[7] += f3.y;
    }

    for (int e = beg; e < end; e += 16) {
        int idx0 = e + g, idx1 = e + 4 + g, idx2 = e + 8 + g, idx3 = e + 12 + g;
        bool b0 = idx0 < end, b1 = idx1 < end, b2 = idx2 < end, b3 = idx3 < end;
        uint2 v0, v1, v2, v3;
        // issue all index loads + gathers before any use (16 edges in flight)
        if (b0) { int s = csr_src[idx0]; v0 = *(const uint2*)&Z[(size_t)s * 128 + fb]; }
        if (b1) { int s = csr_src[idx1]; v1 = *(const uint2*)&Z[(size_t)s * 128 + fb]; }
        if (b2) { int s = csr_src[idx2]; v2 = *(const uint2*)&Z[(size_t)s * 128 + fb]; }
        if (b3) { int s = csr_src[idx3]; v3 = *(const uint2*)&Z[(size_t)s * 128 + fb]; }
        if (b0) {
            f32x2 f0 = fp8x2_lo(v0.x), f1 = fp8x2_hi(v0.x);
            f32x2 f2 = fp8x2_lo(v0.y), f3 = fp8x2_hi(v0.y);
            acc[0] += f0.x; acc[1] += f0.y; acc[2] += f1.x; acc[3] += f1.y;
            acc[4] += f2.x; acc[5] += f2.y; acc[6] += f3.x; acc[7] += f3.y;
        }
        if (b1) {
            f32x2 f0 = fp8x2_lo(v1.x), f1 = fp8x2_hi(v1.x);
            f32x2 f2 = fp8x2_lo(v1.y), f3 = fp8x2_hi(v1.y);
            acc[0] += f0.x; acc[1] += f0.y; acc[2] += f1.x; acc[3] += f1.y;
            acc[4] += f2.x; acc[5] += f2.y; acc[6] += f3.x; acc[7] += f3.y;
        }
        if (b2) {
            f32x2 f0 = fp8x2_lo(v2.x), f1 = fp8x2_hi(v2.x);
            f32x2 f2 = fp8x2_lo(v2.y), f3 = fp8x2_hi(v2.y);
            acc[0] += f0.x; acc[1] += f0.y; acc[2] += f1.x; acc[3] += f1.y;
            acc[4] += f2.x; acc[5] += f2.y; acc[6] += f3.x; acc[7] += f3.y;
        }
        if (b3) {
            f32x2 f0 = fp8x2_lo(v3.x), f1 = fp8x2_hi(v3.x);
            f32x2 f2 = fp8x2_lo(v3.y), f3 = fp8x2_hi(v3.y);
            acc[0] += f0.x; acc[1] += f0.y; acc[2] += f1.x; acc[3] += f1.y;
            acc[4] += f2.x; acc[5] += f2.y; acc[6] += f3.x; acc[7] += f3.y;
        }
    }

    // combine the 4 edge subgroups (butterfly: all lanes end with full sums)
#pragma unroll
    for (int j = 0; j < 8; j++) {
        acc[j] += __shfl_xor(acc[j], 16, 64);
        acc[j] += __shfl_xor(acc[j], 32, 64);
    }

    if (g == 0) {
        float din = dinv[wave];
        float4 bb0 = *(const float4*)&bias[fb];
        float4 bb1 = *(const float4*)&bias[fb + 4];
        float o[8];
        o[0] = din * acc[0] + bb0.x; o[1] = din * acc[1] + bb0.y;
        o[2] = din * acc[2] + bb0.z; o[3] = din * acc[3] + bb0.w;
        o[4] = din * acc[4] + bb1.x; o[5] = din * acc[5] + bb1.y;
        o[6] = din * acc[6] + bb1.z; o[7] = din * acc[7] + bb1.w;
        if (do_relu) {
#pragma unroll
            for (int j = 0; j < 8; j++) o[j] = fmaxf(o[j], 0.f);
        }
        u16 ob[8];
#pragma unroll
        for (int j = 0; j < 8; j++) ob[j] = f2b(o[j]);
        *(uint4*)&OUT[(size_t)wave * 128 + fb] = *(uint4*)ob;
    }
}

// ---------------- mean pool per graph (parallel, batch sorted) ----------------
__global__ __launch_bounds__(64) void k_pool_partial(const u16* __restrict__ H,
                                                     const int* __restrict__ batch, int N,
                                                     float* __restrict__ pooled) {
    int t = threadIdx.x;          // feature pair: 2t, 2t+1
    int chunk = (N + gridDim.x - 1) / gridDim.x;
    int beg = blockIdx.x * chunk;
    int end = beg + chunk; if (end > N) end = N;
    if (beg >= end) return;
    float ax = 0.f, ay = 0.f;
    int g = batch[beg];
    for (int nn = beg; nn < end; ++nn) {
        int gn = batch[nn];
        if (gn != g) {
            atomicAdd(&pooled[g * 128 + 2 * t], ax);
            atomicAdd(&pooled[g * 128 + 2 * t + 1], ay);
            ax = 0.f; ay = 0.f;
            g = gn;
        }
        ushort2 v = *(const ushort2*)&H[(size_t)nn * 128 + 2 * t];
        ax += b2f(v.x); ay += b2f(v.y);
    }
    atomicAdd(&pooled[g * 128 + 2 * t], ax);
    atomicAdd(&pooled[g * 128 + 2 * t + 1], ay);
}

__global__ void k_pool_final(const int* __restrict__ batch, int N,
                             float* __restrict__ pooled) {
    int g = blockIdx.x;
    int t = threadIdx.x;
    __shared__ int sh[2];
    if (t == 0) {
        int lo = 0, hi = N;
        while (lo < hi) { int m = (lo + hi) >> 1; if (batch[m] < g) lo = m + 1; else hi = m; }
        sh[0] = lo;
        lo = 0; hi = N;
        while (lo < hi) { int m = (lo + hi) >> 1; if (batch[m] < g + 1) lo = m + 1; else hi = m; }
        sh[1] = lo;
    }
    __syncthreads();
    float cnt = (float)(sh[1] - sh[0]);
    if (cnt < 1.f) cnt = 1.f;
    pooled[g * 128 + t] /= cnt;
}

// ---------------- final MLP ----------------
__global__ void k_mlp(const float* __restrict__ pooled, const float* __restrict__ Wl1,
                      const float* __restrict__ bl1, const float* __restrict__ Wl2,
                      const float* __restrict__ bl2, float* __restrict__ out) {
    int g = blockIdx.x;
    int j = threadIdx.x;
    float acc = 0.f;
#pragma unroll 8
    for (int k = 0; k < 128; k++) acc += pooled[g * 128 + k] * Wl1[k * 64 + j];
    float h = fmaxf(acc + bl1[j], 0.f);
    float v = h * Wl2[j];
#pragma unroll
    for (int off = 32; off > 0; off >>= 1) v += __shfl_down(v, off);
    if (j == 0) out[g] = 1.f / (1.f + expf(-(v + bl2[0])));
}

// ---------------- launch ----------------
extern "C" void kernel_launch(void* const* d_in, const int* in_sizes, int n_in,
                              void* d_out, int out_size, void* d_ws, size_t ws_size,
                              hipStream_t stream) {
    const float* x    = (const float*)d_in[0];
    const int*   edge = (const int*)d_in[1];
    const int*   batch= (const int*)d_in[2];
    const float* W1   = (const float*)d_in[3];
    const float* b1   = (const float*)d_in[4];
    const float* W2   = (const float*)d_in[5];
    const float* b2   = (const float*)d_in[6];
    const float* Wl1  = (const float*)d_in[7];
    const float* bl1  = (const float*)d_in[8];
    const float* Wl2  = (const float*)d_in[9];
    const float* bl2  = (const float*)d_in[10];
    float* out = (float*)d_out;

    int N = in_sizes[0] / 128;
    int E = in_sizes[1] / 2;
    const int* src = edge;
    const int* dst = edge + E;
    int nbuck = (N + (1 << BSHIFT) - 1) >> BSHIFT;

    char* ws = (char*)d_ws;
    size_t off = 0;
    auto alloc = [&](size_t bytes) { void* p = ws + off; off += (bytes + 511) & ~(size_t)511; return p; };
    float* dinv    = (float*)alloc((size_t)N * 4);
    u8*    Z       = (u8*)alloc((size_t)N * 128);        // fp8 gather buffer
    u16*   H       = (u16*)alloc((size_t)N * 128 * 2);   // bf16 agg output
    int*   row_off = (int*)alloc((size_t)(N + 1) * 4);
    int*   csr_src = (int*)alloc((size_t)E * 4);
    u32*   stage   = (u32*)alloc((size_t)E * 4);
    int*   bcnt    = (int*)alloc(256 * 4);
    int*   bbase   = (int*)alloc(260 * 4);
    int*   bkcur   = (int*)alloc(256 * 4);
    float* pooled  = (float*)alloc(64 * 128 * 4);
    u16*   Wt1     = (u16*)alloc(128 * 128 * 2);
    u16*   Wt2     = (u16*)alloc(128 * 128 * 2);

    hipMemsetAsync(bcnt, 0, 256 * 4, stream);
    hipMemsetAsync(bkcur, 0, 256 * 4, stream);
    hipMemsetAsync(pooled, 0, 64 * 128 * 4, stream);

    k_bhist<<<(E + BH_CHUNK - 1) / BH_CHUNK, 256, 0, stream>>>(dst, E, bcnt, nbuck);
    k_bscan<<<1, 256, 0, stream>>>(bcnt, bbase, row_off, nbuck, N, E);
    k_wt<<<2, 256, 0, stream>>>(W1, W2, Wt1, Wt2);
    k_bucketA<<<(E + EPB - 1) / EPB, 256, 0, stream>>>(src, dst, E, bbase, bkcur, stage, nbuck);
    k_bucketB<<<nbuck, 256, 0, stream>>>(stage, bbase, csr_src, row_off, dinv, N);

    k_gemm_mfma<float><<<(N + 63) / 64, 256, 0, stream>>>(x, Wt1, dinv, Z, N);
    k_agg<<<(N + 3) / 4, 256, 0, stream>>>(Z, dinv, row_off, csr_src, b1, H, N, 1);
    k_gemm_mfma<u16><<<(N + 63) / 64, 256, 0, stream>>>(H, Wt2, dinv, Z, N);
    k_agg<<<(N + 3) / 4, 256, 0, stream>>>(Z, dinv, row_off, csr_src, b2, H, N, 0);
    k_pool_partial<<<2048, 64, 0, stream>>>(H, batch, N, pooled);
    k_pool_final<<<64, 128, 0, stream>>>(batch, N, pooled);
    k_mlp<<<64, 64, 0, stream>>>(pooled, Wl1, bl1, Wl2, bl2, out);
}

// Round 9
// 224.553 us; speedup vs baseline: 12.4399x; 1.2428x over previous
//
#include <hip/hip_runtime.h>
#include <hip/hip_bf16.h>
#include <math.h>

typedef unsigned short u16;
typedef unsigned char u8;
typedef unsigned int u32;
typedef unsigned long long u64;
typedef __attribute__((ext_vector_type(8))) short bf16x8;
typedef __attribute__((ext_vector_type(4))) float f32x4;
typedef __attribute__((ext_vector_type(2))) float f32x2;

__device__ __forceinline__ float b2f(u16 u) {
    union { unsigned int i; float f; } v; v.i = ((unsigned int)u) << 16; return v.f;
}
__device__ __forceinline__ u16 f2b(float f) {
    unsigned int i = __float_as_uint(f);
    unsigned int r = (i + 0x7FFFu + ((i >> 16) & 1u)) >> 16;
    return (u16)r;
}
// fp8 e4m3 HW conversions (gfx950 OCP)
__device__ __forceinline__ f32x2 fp8x2_lo(u32 w) { return __builtin_amdgcn_cvt_pk_f32_fp8((int)w, false); }
__device__ __forceinline__ f32x2 fp8x2_hi(u32 w) { return __builtin_amdgcn_cvt_pk_f32_fp8((int)w, true); }
__device__ __forceinline__ u32 f32x2_to_fp8(float a, float b) {
    return (u32)__builtin_amdgcn_cvt_pk_fp8_f32(a, b, 0, false);
}

#define BSHIFT 9            // 512 nodes per bucket
#define EPB 4096            // edges per bucketA block
#define BH_CHUNK 16384      // edges per bhist block
#define SRC_MASK 0x1FFFFu   // 17 bits (N < 131072)

// ---------------- bucket histogram ----------------
__global__ __launch_bounds__(256) void k_bhist(const int* __restrict__ dst, int E,
                                               int* __restrict__ bcnt, int nbuck) {
    __shared__ int h[256];
    int t = threadIdx.x;
    h[t] = 0;
    __syncthreads();
    int e0 = blockIdx.x * BH_CHUNK;
    int e1 = e0 + BH_CHUNK; if (e1 > E) e1 = E;
    for (int i = e0 + t; i < e1; i += 256) atomicAdd(&h[dst[i] >> BSHIFT], 1);
    __syncthreads();
    if (t < nbuck && h[t] > 0) atomicAdd(&bcnt[t], h[t]);
}

// ---------------- bucket base scan ----------------
__global__ __launch_bounds__(256) void k_bscan(const int* __restrict__ bcnt,
                                               int* __restrict__ bbase,
                                               int* __restrict__ row_off,
                                               int nbuck, int N, int E) {
    __shared__ int lds[256];
    int t = threadIdx.x;
    int mine = (t < nbuck) ? bcnt[t] : 0;
    lds[t] = mine;
    __syncthreads();
    int val = mine;
    for (int s = 1; s < 256; s <<= 1) {
        int add = (t >= s) ? lds[t - s] : 0;
        __syncthreads();
        val += add;
        lds[t] = val;
        __syncthreads();
    }
    if (t < nbuck) bbase[t] = val - mine;
    if (t == nbuck - 1) bbase[nbuck] = val;
    if (t == 0) row_off[N] = E;
}

// ---------------- bucketA: stage edges grouped by dst-bucket ----------------
__global__ __launch_bounds__(256) void k_bucketA(const int* __restrict__ src,
                                                 const int* __restrict__ dst, int E,
                                                 const int* __restrict__ bbase,
                                                 int* __restrict__ bkcur,
                                                 u32* __restrict__ stage, int nbuck) {
    __shared__ int cntL[512];
    __shared__ int prefE[512];
    __shared__ int allocL[512];
    __shared__ int baseL[512];
    __shared__ u64 stageL[EPB];
    int t = threadIdx.x;
    int e0 = blockIdx.x * EPB;

    for (int i = t; i < 512; i += 256) cntL[i] = 0;
    __syncthreads();
#pragma unroll
    for (int j = 0; j < EPB / 256; j++) {
        int e = e0 + j * 256 + t;
        if (e < E) atomicAdd(&cntL[dst[e] >> BSHIFT], 1);
    }
    __syncthreads();
    for (int i = t; i < 512; i += 256) prefE[i] = cntL[i];
    __syncthreads();
    for (int s = 1; s < 512; s <<= 1) {
        int v0 = (t >= s) ? prefE[t - s] : 0;
        int i1 = t + 256;
        int v1 = (i1 >= s) ? prefE[i1 - s] : 0;
        __syncthreads();
        prefE[t] += v0;
        prefE[i1] += v1;
        __syncthreads();
    }
    for (int i = t; i < 512; i += 256) {
        int ex = prefE[i] - cntL[i];
        prefE[i] = ex;
        allocL[i] = ex;
    }
    __syncthreads();
    for (int i = t; i < 512; i += 256) {
        if (i < nbuck && cntL[i] > 0)
            baseL[i] = bbase[i] + atomicAdd(&bkcur[i], cntL[i]);
    }
    __syncthreads();
#pragma unroll
    for (int j = 0; j < EPB / 256; j++) {
        int e = e0 + j * 256 + t;
        if (e < E) {
            int d = dst[e];
            int b = d >> BSHIFT;
            int slot = atomicAdd(&allocL[b], 1);
            stageL[slot] = ((u64)(unsigned)d << 32) | (unsigned)src[e];
        }
    }
    __syncthreads();
    int tot = E - e0; if (tot > EPB) tot = EPB;
    for (int i = t; i < tot; i += 256) {
        u64 v = stageL[i];
        int b = (int)(v >> (32 + BSHIFT));
        u32 d9 = (u32)((v >> 32) & 511u);
        u32 packed = (d9 << 17) | ((u32)v & SRC_MASK);
        stage[baseL[b] + (i - prefE[b])] = packed;
    }
}

// ------- bucketB: local hist+scan -> row_off, dinv, csr placement -------
__global__ __launch_bounds__(256) void k_bucketB(const u32* __restrict__ stage,
                                                 const int* __restrict__ bbase,
                                                 int* __restrict__ csr_src,
                                                 int* __restrict__ row_off,
                                                 float* __restrict__ dinv, int N) {
    __shared__ int hist[512];
    __shared__ int pref[512];
    __shared__ int cur[512];
    int b = blockIdx.x, t = threadIdx.x;
    int node_lo = b << BSHIFT;
    int nloc = N - node_lo; if (nloc > 512) nloc = 512;
    int rbeg = bbase[b], rend = bbase[b + 1];

    for (int i = t; i < 512; i += 256) hist[i] = 0;
    __syncthreads();
    for (int i = rbeg + t; i < rend; i += 256) atomicAdd(&hist[stage[i] >> 17], 1);
    __syncthreads();
    for (int i = t; i < 512; i += 256) pref[i] = hist[i];
    __syncthreads();
    for (int s = 1; s < 512; s <<= 1) {
        int v0 = (t >= s) ? pref[t - s] : 0;
        int i1 = t + 256;
        int v1 = (i1 >= s) ? pref[i1 - s] : 0;
        __syncthreads();
        pref[t] += v0;
        pref[i1] += v1;
        __syncthreads();
    }
    for (int i = t; i < 512; i += 256) {
        int ex = pref[i] - hist[i];
        cur[i] = rbeg + ex;
        if (i < nloc) {
            row_off[node_lo + i] = rbeg + ex;
            dinv[node_lo + i] = rsqrtf((float)(hist[i] + 1));  // +1 self loop
        }
    }
    __syncthreads();
    for (int i = rbeg + t; i < rend; i += 256) {
        u32 v = stage[i];
        int pos = atomicAdd(&cur[v >> 17], 1);
        csr_src[pos] = (int)(v & SRC_MASK);
    }
}

// ---------------- W transpose+bf16 prep ----------------
__global__ void k_wt(const float* __restrict__ W1, const float* __restrict__ W2,
                     u16* __restrict__ Wt1, u16* __restrict__ Wt2) {
    const float* W = blockIdx.x ? W2 : W1;
    u16* Wt = blockIdx.x ? Wt2 : Wt1;
    int t = threadIdx.x;
    for (int i = t; i < 16384; i += 256) {
        int k = i >> 7, c = i & 127;
        Wt[c * 128 + k] = f2b(W[i]);
    }
}

// -------- MFMA GEMM: Z[N,128](fp8) = dinv[r] * (X[N,128] @ W) ----------------
// 128 rows per block (2 row-group passes) to amortize the Wt LDS staging.
template <typename TIN>
__global__ __launch_bounds__(256) void k_gemm_mfma(const TIN* __restrict__ X,
                                                   const u16* __restrict__ Wt,
                                                   const float* __restrict__ dinv,
                                                   u8* __restrict__ Y, int N) {
    __shared__ u16 WtL[128 * 128];
    __shared__ u8 YL[4][16 * 128];
    int t = threadIdx.x;
    {
        const char* gsrc = (const char*)Wt;
        char* lbase = (char*)WtL;
#pragma unroll
        for (int i = 0; i < 8; i++) {
            int byte = (i * 256 + t) * 16;
            int row = byte >> 8;
            int swz = byte ^ ((row & 7) << 4);
            *(uint4*)(lbase + swz) = *(const uint4*)(gsrc + byte);
        }
    }
    __syncthreads();

    int wave = t >> 6, lane = t & 63;
    int lrow = lane & 15, lseg = lane >> 4;
    const char* lbase = (const char*)WtL;
    u8* yw = &YL[wave][0];

#pragma unroll
    for (int rg = 0; rg < 2; rg++) {
        int r0w = blockIdx.x * 128 + rg * 64 + wave * 16;

        bf16x8 a[4];
        {
            int row = r0w + lrow; if (row >= N) row = N - 1;
            if constexpr (sizeof(TIN) == 4) {
                const float* xp = (const float*)X + (size_t)row * 128 + lseg * 8;
#pragma unroll
                for (int j = 0; j < 4; j++) {
                    float4 f0 = *(const float4*)(xp + j * 32);
                    float4 f1 = *(const float4*)(xp + j * 32 + 4);
                    bf16x8 v;
                    v[0] = (short)f2b(f0.x); v[1] = (short)f2b(f0.y);
                    v[2] = (short)f2b(f0.z); v[3] = (short)f2b(f0.w);
                    v[4] = (short)f2b(f1.x); v[5] = (short)f2b(f1.y);
                    v[6] = (short)f2b(f1.z); v[7] = (short)f2b(f1.w);
                    a[j] = v;
                }
            } else {
                const u16* xp = (const u16*)X + (size_t)row * 128 + lseg * 8;
#pragma unroll
                for (int j = 0; j < 4; j++) a[j] = *(const bf16x8*)(xp + j * 32);
            }
        }

        f32x4 acc[8];
#pragma unroll
        for (int c = 0; c < 8; c++) acc[c] = (f32x4){0.f, 0.f, 0.f, 0.f};

#pragma unroll
        for (int c = 0; c < 8; c++) {
            int wrow = c * 16 + lrow;
#pragma unroll
            for (int j = 0; j < 4; j++) {
                int byte = wrow * 256 + (j * 32 + lseg * 8) * 2;
                int swz = byte ^ ((wrow & 7) << 4);
                bf16x8 bf = *(const bf16x8*)(lbase + swz);
                acc[c] = __builtin_amdgcn_mfma_f32_16x16x32_bf16(a[j], bf, acc[c], 0, 0, 0);
            }
        }

        float dv[4];
        int rowb = r0w + lseg * 4;
#pragma unroll
        for (int r = 0; r < 4; r++) {
            int row = rowb + r;
            dv[r] = (row < N) ? dinv[row] : 0.f;
        }
#pragma unroll
        for (int c = 0; c < 8; c++) {
            u32 p01 = f32x2_to_fp8(acc[c][0] * dv[0], acc[c][1] * dv[1]);
            u32 p23 = f32x2_to_fp8(acc[c][2] * dv[2], acc[c][3] * dv[3]);
            int base = (lseg * 4) * 128 + c * 16 + lrow;
            yw[base]           = (u8)p01;
            yw[base + 128]     = (u8)(p01 >> 8);
            yw[base + 256]     = (u8)p23;
            yw[base + 384]     = (u8)(p23 >> 8);
        }
#pragma unroll
        for (int k = 0; k < 2; k++) {
            int idx = lane + 64 * k;
            int row = idx >> 3;
            int seg = idx & 7;
            int grow = r0w + row;
            uint4 v = *(const uint4*)&yw[row * 128 + seg * 16];
            if (grow < N) *(uint4*)&Y[(size_t)grow * 128 + seg * 16] = v;
        }
    }
}

// -------- aggregation: wave/node; chunked index preload + unconditional
// weighted gathers (no load-use guards -> compiler keeps gathers in flight) ---
__global__ __launch_bounds__(256) void k_agg(const u8* __restrict__ Z,
                                             const float* __restrict__ dinv,
                                             const int* __restrict__ row_off,
                                             const int* __restrict__ csr_src,
                                             const float* __restrict__ bias,
                                             u16* __restrict__ OUT, int N, int do_relu) {
    int wave = (blockIdx.x * blockDim.x + threadIdx.x) >> 6;
    int lane = threadIdx.x & 63;
    if (wave >= N) return;
    int g = lane >> 4;          // edge subgroup 0..3
    int fb = (lane & 15) * 8;   // feature base: 8 features per lane
    int beg = row_off[wave], end = row_off[wave + 1];

    float acc[8];
#pragma unroll
    for (int j = 0; j < 8; j++) acc[j] = 0.f;

    // self loop: group 0 only (Z already prescaled by dinv)
    if (g == 0) {
        uint2 v = *(const uint2*)&Z[(size_t)wave * 128 + fb];
        f32x2 f0 = fp8x2_lo(v.x), f1 = fp8x2_hi(v.x);
        f32x2 f2 = fp8x2_lo(v.y), f3 = fp8x2_hi(v.y);
        acc[0] += f0.x; acc[1] += f0.y; acc[2] += f1.x; acc[3] += f1.y;
        acc[4] += f2.x; acc[5] += f2.y; acc[6] += f3.x; acc[7] += f3.y;
    }

    for (int base = beg; base < end; base += 64) {
        int nc = end - base; if (nc > 64) nc = 64;   // edges in this chunk
        // one vector load: 64 indices for the whole wave
        int ii = base + lane; if (ii > end - 1) ii = end - 1;
        int idx = csr_src[ii];
#pragma unroll
        for (int k = 0; k < 4; k++) {
            if (k && k * 16 >= nc) break;            // wave-uniform skip
            int eo = k * 16 + g;                     // this group's edge offset
            int sl = eo < nc ? eo : nc - 1;
            float w = (eo < nc) ? 1.f : 0.f;
            int s = __shfl(idx, sl, 64);
            uint2 v = *(const uint2*)&Z[(size_t)s * 128 + fb];
            f32x2 f0 = fp8x2_lo(v.x), f1 = fp8x2_hi(v.x);
            f32x2 f2 = fp8x2_lo(v.y), f3 = fp8x2_hi(v.y);
            acc[0] = fmaf(w, f0.x, acc[0]); acc[1] = fmaf(w, f0.y, acc[1]);
            acc[2] = fmaf(w, f1.x, acc[2]); acc[3] = fmaf(w, f1.y, acc[3]);
            acc[4] = fmaf(w, f2.x, acc[4]); acc[5] = fmaf(w, f2.y, acc[5]);
            acc[6] = fmaf(w, f3.x, acc[6]); acc[7] = fmaf(w, f3.y, acc[7]);
        }
    }

    // combine the 4 edge subgroups (butterfly: all lanes end with full sums)
#pragma unroll
    for (int j = 0; j < 8; j++) {
        acc[j] += __shfl_xor(acc[j], 16, 64);
        acc[j] += __shfl_xor(acc[j], 32, 64);
    }

    if (g == 0) {
        float din = dinv[wave];
        float4 bb0 = *(const float4*)&bias[fb];
        float4 bb1 = *(const float4*)&bias[fb + 4];
        float o[8];
        o[0] = din * acc[0] + bb0.x; o[1] = din * acc[1] + bb0.y;
        o[2] = din * acc[2] + bb0.z; o[3] = din * acc[3] + bb0.w;
        o[4] = din * acc[4] + bb1.x; o[5] = din * acc[5] + bb1.y;
        o[6] = din * acc[6] + bb1.z; o[7] = din * acc[7] + bb1.w;
        if (do_relu) {
#pragma unroll
            for (int j = 0; j < 8; j++) o[j] = fmaxf(o[j], 0.f);
        }
        u16 ob[8];
#pragma unroll
        for (int j = 0; j < 8; j++) ob[j] = f2b(o[j]);
        *(uint4*)&OUT[(size_t)wave * 128 + fb] = *(uint4*)ob;
    }
}

// ---------------- mean pool per graph (parallel, batch sorted) ----------------
__global__ __launch_bounds__(64) void k_pool_partial(const u16* __restrict__ H,
                                                     const int* __restrict__ batch, int N,
                                                     float* __restrict__ pooled) {
    int t = threadIdx.x;          // feature pair: 2t, 2t+1
    int chunk = (N + gridDim.x - 1) / gridDim.x;
    int beg = blockIdx.x * chunk;
    int end = beg + chunk; if (end > N) end = N;
    if (beg >= end) return;
    float ax = 0.f, ay = 0.f;
    int g = batch[beg];
    for (int nn = beg; nn < end; ++nn) {
        int gn = batch[nn];
        if (gn != g) {
            atomicAdd(&pooled[g * 128 + 2 * t], ax);
            atomicAdd(&pooled[g * 128 + 2 * t + 1], ay);
            ax = 0.f; ay = 0.f;
            g = gn;
        }
        ushort2 v = *(const ushort2*)&H[(size_t)nn * 128 + 2 * t];
        ax += b2f(v.x); ay += b2f(v.y);
    }
    atomicAdd(&pooled[g * 128 + 2 * t], ax);
    atomicAdd(&pooled[g * 128 + 2 * t + 1], ay);
}

__global__ void k_pool_final(const int* __restrict__ batch, int N,
                             float* __restrict__ pooled) {
    int g = blockIdx.x;
    int t = threadIdx.x;
    __shared__ int sh[2];
    if (t == 0) {
        int lo = 0, hi = N;
        while (lo < hi) { int m = (lo + hi) >> 1; if (batch[m] < g) lo = m + 1; else hi = m; }
        sh[0] = lo;
        lo = 0; hi = N;
        while (lo < hi) { int m = (lo + hi) >> 1; if (batch[m] < g + 1) lo = m + 1; else hi = m; }
        sh[1] = lo;
    }
    __syncthreads();
    float cnt = (float)(sh[1] - sh[0]);
    if (cnt < 1.f) cnt = 1.f;
    pooled[g * 128 + t] /= cnt;
}

// ---------------- final MLP ----------------
__global__ void k_mlp(const float* __restrict__ pooled, const float* __restrict__ Wl1,
                      const float* __restrict__ bl1, const float* __restrict__ Wl2,
                      const float* __restrict__ bl2, float* __restrict__ out) {
    int g = blockIdx.x;
    int j = threadIdx.x;
    float acc = 0.f;
#pragma unroll 8
    for (int k = 0; k < 128; k++) acc += pooled[g * 128 + k] * Wl1[k * 64 + j];
    float h = fmaxf(acc + bl1[j], 0.f);
    float v = h * Wl2[j];
#pragma unroll
    for (int off = 32; off > 0; off >>= 1) v += __shfl_down(v, off);
    if (j == 0) out[g] = 1.f / (1.f + expf(-(v + bl2[0])));
}

// ---------------- launch ----------------
extern "C" void kernel_launch(void* const* d_in, const int* in_sizes, int n_in,
                              void* d_out, int out_size, void* d_ws, size_t ws_size,
                              hipStream_t stream) {
    const float* x    = (const float*)d_in[0];
    const int*   edge = (const int*)d_in[1];
    const int*   batch= (const int*)d_in[2];
    const float* W1   = (const float*)d_in[3];
    const float* b1   = (const float*)d_in[4];
    const float* W2   = (const float*)d_in[5];
    const float* b2   = (const float*)d_in[6];
    const float* Wl1  = (const float*)d_in[7];
    const float* bl1  = (const float*)d_in[8];
    const float* Wl2  = (const float*)d_in[9];
    const float* bl2  = (const float*)d_in[10];
    float* out = (float*)d_out;

    int N = in_sizes[0] / 128;
    int E = in_sizes[1] / 2;
    const int* src = edge;
    const int* dst = edge + E;
    int nbuck = (N + (1 << BSHIFT) - 1) >> BSHIFT;

    char* ws = (char*)d_ws;
    size_t off = 0;
    auto alloc = [&](size_t bytes) { void* p = ws + off; off += (bytes + 511) & ~(size_t)511; return p; };
    float* dinv    = (float*)alloc((size_t)N * 4);
    u8*    Z       = (u8*)alloc((size_t)N * 128);        // fp8 gather buffer
    u16*   H       = (u16*)alloc((size_t)N * 128 * 2);   // bf16 agg output
    int*   row_off = (int*)alloc((size_t)(N + 1) * 4);
    int*   csr_src = (int*)alloc((size_t)E * 4);
    u32*   stage   = (u32*)alloc((size_t)E * 4);
    int*   bcnt    = (int*)alloc(256 * 4);
    int*   bbase   = (int*)alloc(260 * 4);
    int*   bkcur   = (int*)alloc(256 * 4);
    float* pooled  = (float*)alloc(64 * 128 * 4);
    u16*   Wt1     = (u16*)alloc(128 * 128 * 2);
    u16*   Wt2     = (u16*)alloc(128 * 128 * 2);

    hipMemsetAsync(bcnt, 0, 256 * 4, stream);
    hipMemsetAsync(bkcur, 0, 256 * 4, stream);
    hipMemsetAsync(pooled, 0, 64 * 128 * 4, stream);

    k_bhist<<<(E + BH_CHUNK - 1) / BH_CHUNK, 256, 0, stream>>>(dst, E, bcnt, nbuck);
    k_bscan<<<1, 256, 0, stream>>>(bcnt, bbase, row_off, nbuck, N, E);
    k_wt<<<2, 256, 0, stream>>>(W1, W2, Wt1, Wt2);
    k_bucketA<<<(E + EPB - 1) / EPB, 256, 0, stream>>>(src, dst, E, bbase, bkcur, stage, nbuck);
    k_bucketB<<<nbuck, 256, 0, stream>>>(stage, bbase, csr_src, row_off, dinv, N);

    k_gemm_mfma<float><<<(N + 127) / 128, 256, 0, stream>>>(x, Wt1, dinv, Z, N);
    k_agg<<<(N + 3) / 4, 256, 0, stream>>>(Z, dinv, row_off, csr_src, b1, H, N, 1);
    k_gemm_mfma<u16><<<(N + 127) / 128, 256, 0, stream>>>(H, Wt2, dinv, Z, N);
    k_agg<<<(N + 3) / 4, 256, 0, stream>>>(Z, dinv, row_off, csr_src, b2, H, N, 0);
    k_pool_partial<<<2048, 64, 0, stream>>>(H, batch, N, pooled);
    k_pool_final<<<64, 128, 0, stream>>>(batch, N, pooled);
    k_mlp<<<64, 64, 0, stream>>>(pooled, Wl1, bl1, Wl2, bl2, out);
}

// Round 10
// 212.533 us; speedup vs baseline: 13.1434x; 1.0566x over previous
//
#include <hip/hip_runtime.h>
#include <hip/hip_bf16.h>
#include <math.h>

typedef unsigned short u16;
typedef unsigned char u8;
typedef unsigned int u32;
typedef unsigned long long u64;
typedef __attribute__((ext_vector_type(8))) short bf16x8;
typedef __attribute__((ext_vector_type(4))) float f32x4;
typedef __attribute__((ext_vector_type(2))) float f32x2;

__device__ __forceinline__ float b2f(u16 u) {
    union { unsigned int i; float f; } v; v.i = ((unsigned int)u) << 16; return v.f;
}
__device__ __forceinline__ u16 f2b(float f) {
    unsigned int i = __float_as_uint(f);
    unsigned int r = (i + 0x7FFFu + ((i >> 16) & 1u)) >> 16;
    return (u16)r;
}
// fp8 e4m3 HW conversions (gfx950 OCP)
__device__ __forceinline__ f32x2 fp8x2_lo(u32 w) { return __builtin_amdgcn_cvt_pk_f32_fp8((int)w, false); }
__device__ __forceinline__ f32x2 fp8x2_hi(u32 w) { return __builtin_amdgcn_cvt_pk_f32_fp8((int)w, true); }
__device__ __forceinline__ u32 f32x2_to_fp8(float a, float b) {
    return (u32)__builtin_amdgcn_cvt_pk_fp8_f32(a, b, 0, false);
}

#define BSHIFT 9            // 512 nodes per bucket
#define EPB 4096            // edges per bucketA block
#define BH_CHUNK 16384      // edges per bhist block
#define SRC_MASK 0x1FFFFu   // 17 bits (N < 131072)

// ---------------- init: zero bcnt, bkcur, pooled (replaces 3 memsets) --------
__global__ __launch_bounds__(256) void k_init(int* __restrict__ bcnt,
                                              int* __restrict__ bkcur,
                                              float* __restrict__ pooled) {
    int t = threadIdx.x;
    int b = blockIdx.x;
    if (b == 0) { bcnt[t] = 0; bkcur[t] = 0; }
    else {
        int i = (b - 1) * 256 + t;
        if (i < 64 * 128) pooled[i] = 0.f;
    }
}

// ---------------- bucket histogram ----------------
__global__ __launch_bounds__(256) void k_bhist(const int* __restrict__ dst, int E,
                                               int* __restrict__ bcnt, int nbuck) {
    __shared__ int h[256];
    int t = threadIdx.x;
    h[t] = 0;
    __syncthreads();
    int e0 = blockIdx.x * BH_CHUNK;
    int e1 = e0 + BH_CHUNK; if (e1 > E) e1 = E;
    for (int i = e0 + t; i < e1; i += 256) atomicAdd(&h[dst[i] >> BSHIFT], 1);
    __syncthreads();
    if (t < nbuck && h[t] > 0) atomicAdd(&bcnt[t], h[t]);
}

// ---------------- bucket base scan ----------------
__global__ __launch_bounds__(256) void k_bscan(const int* __restrict__ bcnt,
                                               int* __restrict__ bbase,
                                               int* __restrict__ row_off,
                                               int nbuck, int N, int E) {
    __shared__ int lds[256];
    int t = threadIdx.x;
    int mine = (t < nbuck) ? bcnt[t] : 0;
    lds[t] = mine;
    __syncthreads();
    int val = mine;
    for (int s = 1; s < 256; s <<= 1) {
        int add = (t >= s) ? lds[t - s] : 0;
        __syncthreads();
        val += add;
        lds[t] = val;
        __syncthreads();
    }
    if (t < nbuck) bbase[t] = val - mine;
    if (t == nbuck - 1) bbase[nbuck] = val;
    if (t == 0) row_off[N] = E;
}

// ---------------- bucketA: stage edges grouped by dst-bucket ----------------
__global__ __launch_bounds__(256) void k_bucketA(const int* __restrict__ src,
                                                 const int* __restrict__ dst, int E,
                                                 const int* __restrict__ bbase,
                                                 int* __restrict__ bkcur,
                                                 u32* __restrict__ stage, int nbuck) {
    __shared__ int cntL[512];
    __shared__ int prefE[512];
    __shared__ int allocL[512];
    __shared__ int baseL[512];
    __shared__ u64 stageL[EPB];
    int t = threadIdx.x;
    int e0 = blockIdx.x * EPB;

    for (int i = t; i < 512; i += 256) cntL[i] = 0;
    __syncthreads();
#pragma unroll
    for (int j = 0; j < EPB / 256; j++) {
        int e = e0 + j * 256 + t;
        if (e < E) atomicAdd(&cntL[dst[e] >> BSHIFT], 1);
    }
    __syncthreads();
    for (int i = t; i < 512; i += 256) prefE[i] = cntL[i];
    __syncthreads();
    for (int s = 1; s < 512; s <<= 1) {
        int v0 = (t >= s) ? prefE[t - s] : 0;
        int i1 = t + 256;
        int v1 = (i1 >= s) ? prefE[i1 - s] : 0;
        __syncthreads();
        prefE[t] += v0;
        prefE[i1] += v1;
        __syncthreads();
    }
    for (int i = t; i < 512; i += 256) {
        int ex = prefE[i] - cntL[i];
        prefE[i] = ex;
        allocL[i] = ex;
    }
    __syncthreads();
    for (int i = t; i < 512; i += 256) {
        if (i < nbuck && cntL[i] > 0)
            baseL[i] = bbase[i] + atomicAdd(&bkcur[i], cntL[i]);
    }
    __syncthreads();
#pragma unroll
    for (int j = 0; j < EPB / 256; j++) {
        int e = e0 + j * 256 + t;
        if (e < E) {
            int d = dst[e];
            int b = d >> BSHIFT;
            int slot = atomicAdd(&allocL[b], 1);
            stageL[slot] = ((u64)(unsigned)d << 32) | (unsigned)src[e];
        }
    }
    __syncthreads();
    int tot = E - e0; if (tot > EPB) tot = EPB;
    for (int i = t; i < tot; i += 256) {
        u64 v = stageL[i];
        int b = (int)(v >> (32 + BSHIFT));
        u32 d9 = (u32)((v >> 32) & 511u);
        u32 packed = (d9 << 17) | ((u32)v & SRC_MASK);
        stage[baseL[b] + (i - prefE[b])] = packed;
    }
}

// ------- bucketB: local hist+scan -> row_off, dinv, csr placement -------
__global__ __launch_bounds__(256) void k_bucketB(const u32* __restrict__ stage,
                                                 const int* __restrict__ bbase,
                                                 int* __restrict__ csr_src,
                                                 int* __restrict__ row_off,
                                                 float* __restrict__ dinv, int N) {
    __shared__ int hist[512];
    __shared__ int pref[512];
    __shared__ int cur[512];
    int b = blockIdx.x, t = threadIdx.x;
    int node_lo = b << BSHIFT;
    int nloc = N - node_lo; if (nloc > 512) nloc = 512;
    int rbeg = bbase[b], rend = bbase[b + 1];

    for (int i = t; i < 512; i += 256) hist[i] = 0;
    __syncthreads();
    for (int i = rbeg + t; i < rend; i += 256) atomicAdd(&hist[stage[i] >> 17], 1);
    __syncthreads();
    for (int i = t; i < 512; i += 256) pref[i] = hist[i];
    __syncthreads();
    for (int s = 1; s < 512; s <<= 1) {
        int v0 = (t >= s) ? pref[t - s] : 0;
        int i1 = t + 256;
        int v1 = (i1 >= s) ? pref[i1 - s] : 0;
        __syncthreads();
        pref[t] += v0;
        pref[i1] += v1;
        __syncthreads();
    }
    for (int i = t; i < 512; i += 256) {
        int ex = pref[i] - hist[i];
        cur[i] = rbeg + ex;
        if (i < nloc) {
            row_off[node_lo + i] = rbeg + ex;
            dinv[node_lo + i] = rsqrtf((float)(hist[i] + 1));  // +1 self loop
        }
    }
    __syncthreads();
    for (int i = rbeg + t; i < rend; i += 256) {
        u32 v = stage[i];
        int pos = atomicAdd(&cur[v >> 17], 1);
        csr_src[pos] = (int)(v & SRC_MASK);
    }
}

// ---------------- W transpose+bf16 prep ----------------
__global__ void k_wt(const float* __restrict__ W1, const float* __restrict__ W2,
                     u16* __restrict__ Wt1, u16* __restrict__ Wt2) {
    const float* W = blockIdx.x ? W2 : W1;
    u16* Wt = blockIdx.x ? Wt2 : Wt1;
    int t = threadIdx.x;
    for (int i = t; i < 16384; i += 256) {
        int k = i >> 7, c = i & 127;
        Wt[c * 128 + k] = f2b(W[i]);
    }
}

// -------- MFMA GEMM: Z[N,128](fp8) = dinv[r] * (X[N,128] @ W) ----------------
template <typename TIN>
__global__ __launch_bounds__(256) void k_gemm_mfma(const TIN* __restrict__ X,
                                                   const u16* __restrict__ Wt,
                                                   const float* __restrict__ dinv,
                                                   u8* __restrict__ Y, int N) {
    __shared__ u16 WtL[128 * 128];
    __shared__ u8 YL[4][16 * 128];
    int t = threadIdx.x;
    {
        const char* gsrc = (const char*)Wt;
        char* lbase = (char*)WtL;
#pragma unroll
        for (int i = 0; i < 8; i++) {
            int byte = (i * 256 + t) * 16;
            int row = byte >> 8;
            int swz = byte ^ ((row & 7) << 4);
            *(uint4*)(lbase + swz) = *(const uint4*)(gsrc + byte);
        }
    }
    __syncthreads();

    int wave = t >> 6, lane = t & 63;
    int lrow = lane & 15, lseg = lane >> 4;
    const char* lbase = (const char*)WtL;
    u8* yw = &YL[wave][0];

#pragma unroll
    for (int rg = 0; rg < 2; rg++) {
        int r0w = blockIdx.x * 128 + rg * 64 + wave * 16;

        bf16x8 a[4];
        {
            int row = r0w + lrow; if (row >= N) row = N - 1;
            if constexpr (sizeof(TIN) == 4) {
                const float* xp = (const float*)X + (size_t)row * 128 + lseg * 8;
#pragma unroll
                for (int j = 0; j < 4; j++) {
                    float4 f0 = *(const float4*)(xp + j * 32);
                    float4 f1 = *(const float4*)(xp + j * 32 + 4);
                    bf16x8 v;
                    v[0] = (short)f2b(f0.x); v[1] = (short)f2b(f0.y);
                    v[2] = (short)f2b(f0.z); v[3] = (short)f2b(f0.w);
                    v[4] = (short)f2b(f1.x); v[5] = (short)f2b(f1.y);
                    v[6] = (short)f2b(f1.z); v[7] = (short)f2b(f1.w);
                    a[j] = v;
                }
            } else {
                const u16* xp = (const u16*)X + (size_t)row * 128 + lseg * 8;
#pragma unroll
                for (int j = 0; j < 4; j++) a[j] = *(const bf16x8*)(xp + j * 32);
            }
        }

        f32x4 acc[8];
#pragma unroll
        for (int c = 0; c < 8; c++) acc[c] = (f32x4){0.f, 0.f, 0.f, 0.f};

#pragma unroll
        for (int c = 0; c < 8; c++) {
            int wrow = c * 16 + lrow;
#pragma unroll
            for (int j = 0; j < 4; j++) {
                int byte = wrow * 256 + (j * 32 + lseg * 8) * 2;
                int swz = byte ^ ((wrow & 7) << 4);
                bf16x8 bf = *(const bf16x8*)(lbase + swz);
                acc[c] = __builtin_amdgcn_mfma_f32_16x16x32_bf16(a[j], bf, acc[c], 0, 0, 0);
            }
        }

        float dv[4];
        int rowb = r0w + lseg * 4;
#pragma unroll
        for (int r = 0; r < 4; r++) {
            int row = rowb + r;
            dv[r] = (row < N) ? dinv[row] : 0.f;
        }
#pragma unroll
        for (int c = 0; c < 8; c++) {
            u32 p01 = f32x2_to_fp8(acc[c][0] * dv[0], acc[c][1] * dv[1]);
            u32 p23 = f32x2_to_fp8(acc[c][2] * dv[2], acc[c][3] * dv[3]);
            int base = (lseg * 4) * 128 + c * 16 + lrow;
            yw[base]           = (u8)p01;
            yw[base + 128]     = (u8)(p01 >> 8);
            yw[base + 256]     = (u8)p23;
            yw[base + 384]     = (u8)(p23 >> 8);
        }
#pragma unroll
        for (int k = 0; k < 2; k++) {
            int idx = lane + 64 * k;
            int row = idx >> 3;
            int seg = idx & 7;
            int grow = r0w + row;
            uint4 v = *(const uint4*)&yw[row * 128 + seg * 16];
            if (grow < N) *(uint4*)&Y[(size_t)grow * 128 + seg * 16] = v;
        }
    }
}

// -------- aggregation: TWO nodes per wave (doubles independent gather
// streams for latency hiding). 16-lane groups gather 4 edges/instruction;
// unconditional clamped gathers with weight in {0,1}; butterfly combine;
// group 0 stores n0, group 1 stores n1. Per-node accumulation order is
// identical to the 1-node version (absmax stable). ----------------------------
__global__ __launch_bounds__(256) void k_agg(const u8* __restrict__ Z,
                                             const float* __restrict__ dinv,
                                             const int* __restrict__ row_off,
                                             const int* __restrict__ csr_src,
                                             const float* __restrict__ bias,
                                             u16* __restrict__ OUT, int N, int do_relu) {
    int wv = (blockIdx.x * blockDim.x + threadIdx.x) >> 6;
    int lane = threadIdx.x & 63;
    int n0 = wv * 2, n1 = n0 + 1;
    if (n0 >= N) return;
    bool has1 = n1 < N;
    int g = lane >> 4;          // edge subgroup 0..3
    int fb = (lane & 15) * 8;   // feature base: 8 features per lane

    int beg0 = row_off[n0], end0 = row_off[n0 + 1];
    int beg1 = beg0, end1 = beg0;
    if (has1) { beg1 = end0; end1 = row_off[n1 + 1]; }

    float acc0[8], acc1[8];
#pragma unroll
    for (int j = 0; j < 8; j++) { acc0[j] = 0.f; acc1[j] = 0.f; }

    // self loops (Z already prescaled by dinv): group 0 -> n0, group 1 -> n1
    if (g == 0) {
        uint2 v = *(const uint2*)&Z[(size_t)n0 * 128 + fb];
        f32x2 f0 = fp8x2_lo(v.x), f1 = fp8x2_hi(v.x);
        f32x2 f2 = fp8x2_lo(v.y), f3 = fp8x2_hi(v.y);
        acc0[0] += f0.x; acc0[1] += f0.y; acc0[2] += f1.x; acc0[3] += f1.y;
        acc0[4] += f2.x; acc0[5] += f2.y; acc0[6] += f3.x; acc0[7] += f3.y;
    }
    if (g == 1 && has1) {
        uint2 v = *(const uint2*)&Z[(size_t)n1 * 128 + fb];
        f32x2 f0 = fp8x2_lo(v.x), f1 = fp8x2_hi(v.x);
        f32x2 f2 = fp8x2_lo(v.y), f3 = fp8x2_hi(v.y);
        acc1[0] += f0.x; acc1[1] += f0.y; acc1[2] += f1.x; acc1[3] += f1.y;
        acc1[4] += f2.x; acc1[5] += f2.y; acc1[6] += f3.x; acc1[7] += f3.y;
    }

    int base0 = beg0, base1 = beg1;
    while (base0 < end0 || base1 < end1) {
        bool h0 = base0 < end0, h1 = base1 < end1;   // wave-uniform
        int idx0 = 0, idx1 = 0;
        if (h0) { int ii = base0 + lane; if (ii > end0 - 1) ii = end0 - 1; idx0 = csr_src[ii]; }
        if (h1) { int ii = base1 + lane; if (ii > end1 - 1) ii = end1 - 1; idx1 = csr_src[ii]; }
        if (h0) {
            int nc = end0 - base0; if (nc > 64) nc = 64;
#pragma unroll
            for (int k = 0; k < 4; k++) {
                if (k && k * 16 >= nc) break;        // wave-uniform skip
                int eo = k * 16 + g;
                int sl = eo < nc ? eo : nc - 1;
                float w = (eo < nc) ? 1.f : 0.f;
                int s = __shfl(idx0, sl, 64);
                uint2 v = *(const uint2*)&Z[(size_t)s * 128 + fb];
                f32x2 f0 = fp8x2_lo(v.x), f1 = fp8x2_hi(v.x);
                f32x2 f2 = fp8x2_lo(v.y), f3 = fp8x2_hi(v.y);
                acc0[0] = fmaf(w, f0.x, acc0[0]); acc0[1] = fmaf(w, f0.y, acc0[1]);
                acc0[2] = fmaf(w, f1.x, acc0[2]); acc0[3] = fmaf(w, f1.y, acc0[3]);
                acc0[4] = fmaf(w, f2.x, acc0[4]); acc0[5] = fmaf(w, f2.y, acc0[5]);
                acc0[6] = fmaf(w, f3.x, acc0[6]); acc0[7] = fmaf(w, f3.y, acc0[7]);
            }
        }
        if (h1) {
            int nc = end1 - base1; if (nc > 64) nc = 64;
#pragma unroll
            for (int k = 0; k < 4; k++) {
                if (k && k * 16 >= nc) break;
                int eo = k * 16 + g;
                int sl = eo < nc ? eo : nc - 1;
                float w = (eo < nc) ? 1.f : 0.f;
                int s = __shfl(idx1, sl, 64);
                uint2 v = *(const uint2*)&Z[(size_t)s * 128 + fb];
                f32x2 f0 = fp8x2_lo(v.x), f1 = fp8x2_hi(v.x);
                f32x2 f2 = fp8x2_lo(v.y), f3 = fp8x2_hi(v.y);
                acc1[0] = fmaf(w, f0.x, acc1[0]); acc1[1] = fmaf(w, f0.y, acc1[1]);
                acc1[2] = fmaf(w, f1.x, acc1[2]); acc1[3] = fmaf(w, f1.y, acc1[3]);
                acc1[4] = fmaf(w, f2.x, acc1[4]); acc1[5] = fmaf(w, f2.y, acc1[5]);
                acc1[6] = fmaf(w, f3.x, acc1[6]); acc1[7] = fmaf(w, f3.y, acc1[7]);
            }
        }
        base0 += 64; base1 += 64;
    }

    // combine the 4 edge subgroups for both nodes
#pragma unroll
    for (int j = 0; j < 8; j++) {
        acc0[j] += __shfl_xor(acc0[j], 16, 64);
        acc0[j] += __shfl_xor(acc0[j], 32, 64);
        acc1[j] += __shfl_xor(acc1[j], 16, 64);
        acc1[j] += __shfl_xor(acc1[j], 32, 64);
    }

    if (g == 0 || (g == 1 && has1)) {
        int n = (g == 0) ? n0 : n1;
        float din = dinv[n];
        float4 bb0 = *(const float4*)&bias[fb];
        float4 bb1 = *(const float4*)&bias[fb + 4];
        float a[8];
#pragma unroll
        for (int j = 0; j < 8; j++) a[j] = (g == 0) ? acc0[j] : acc1[j];
        float o[8];
        o[0] = din * a[0] + bb0.x; o[1] = din * a[1] + bb0.y;
        o[2] = din * a[2] + bb0.z; o[3] = din * a[3] + bb0.w;
        o[4] = din * a[4] + bb1.x; o[5] = din * a[5] + bb1.y;
        o[6] = din * a[6] + bb1.z; o[7] = din * a[7] + bb1.w;
        if (do_relu) {
#pragma unroll
            for (int j = 0; j < 8; j++) o[j] = fmaxf(o[j], 0.f);
        }
        u16 ob[8];
#pragma unroll
        for (int j = 0; j < 8; j++) ob[j] = f2b(o[j]);
        *(uint4*)&OUT[(size_t)n * 128 + fb] = *(uint4*)ob;
    }
}

// ---------------- mean pool per graph (parallel, batch sorted) ----------------
__global__ __launch_bounds__(64) void k_pool_partial(const u16* __restrict__ H,
                                                     const int* __restrict__ batch, int N,
                                                     float* __restrict__ pooled) {
    int t = threadIdx.x;          // feature pair: 2t, 2t+1
    int chunk = (N + gridDim.x - 1) / gridDim.x;
    int beg = blockIdx.x * chunk;
    int end = beg + chunk; if (end > N) end = N;
    if (beg >= end) return;
    float ax = 0.f, ay = 0.f;
    int g = batch[beg];
    for (int nn = beg; nn < end; ++nn) {
        int gn = batch[nn];
        if (gn != g) {
            atomicAdd(&pooled[g * 128 + 2 * t], ax);
            atomicAdd(&pooled[g * 128 + 2 * t + 1], ay);
            ax = 0.f; ay = 0.f;
            g = gn;
        }
        ushort2 v = *(const ushort2*)&H[(size_t)nn * 128 + 2 * t];
        ax += b2f(v.x); ay += b2f(v.y);
    }
    atomicAdd(&pooled[g * 128 + 2 * t], ax);
    atomicAdd(&pooled[g * 128 + 2 * t + 1], ay);
}

__global__ void k_pool_final(const int* __restrict__ batch, int N,
                             float* __restrict__ pooled) {
    int g = blockIdx.x;
    int t = threadIdx.x;
    __shared__ int sh[2];
    if (t == 0) {
        int lo = 0, hi = N;
        while (lo < hi) { int m = (lo + hi) >> 1; if (batch[m] < g) lo = m + 1; else hi = m; }
        sh[0] = lo;
        lo = 0; hi = N;
        while (lo < hi) { int m = (lo + hi) >> 1; if (batch[m] < g + 1) lo = m + 1; else hi = m; }
        sh[1] = lo;
    }
    __syncthreads();
    float cnt = (float)(sh[1] - sh[0]);
    if (cnt < 1.f) cnt = 1.f;
    pooled[g * 128 + t] /= cnt;
}

// ---------------- final MLP ----------------
__global__ void k_mlp(const float* __restrict__ pooled, const float* __restrict__ Wl1,
                      const float* __restrict__ bl1, const float* __restrict__ Wl2,
                      const float* __restrict__ bl2, float* __restrict__ out) {
    int g = blockIdx.x;
    int j = threadIdx.x;
    float acc = 0.f;
#pragma unroll 8
    for (int k = 0; k < 128; k++) acc += pooled[g * 128 + k] * Wl1[k * 64 + j];
    float h = fmaxf(acc + bl1[j], 0.f);
    float v = h * Wl2[j];
#pragma unroll
    for (int off = 32; off > 0; off >>= 1) v += __shfl_down(v, off);
    if (j == 0) out[g] = 1.f / (1.f + expf(-(v + bl2[0])));
}

// ---------------- launch ----------------
extern "C" void kernel_launch(void* const* d_in, const int* in_sizes, int n_in,
                              void* d_out, int out_size, void* d_ws, size_t ws_size,
                              hipStream_t stream) {
    const float* x    = (const float*)d_in[0];
    const int*   edge = (const int*)d_in[1];
    const int*   batch= (const int*)d_in[2];
    const float* W1   = (const float*)d_in[3];
    const float* b1   = (const float*)d_in[4];
    const float* W2   = (const float*)d_in[5];
    const float* b2   = (const float*)d_in[6];
    const float* Wl1  = (const float*)d_in[7];
    const float* bl1  = (const float*)d_in[8];
    const float* Wl2  = (const float*)d_in[9];
    const float* bl2  = (const float*)d_in[10];
    float* out = (float*)d_out;

    int N = in_sizes[0] / 128;
    int E = in_sizes[1] / 2;
    const int* src = edge;
    const int* dst = edge + E;
    int nbuck = (N + (1 << BSHIFT) - 1) >> BSHIFT;

    char* ws = (char*)d_ws;
    size_t off = 0;
    auto alloc = [&](size_t bytes) { void* p = ws + off; off += (bytes + 511) & ~(size_t)511; return p; };
    float* dinv    = (float*)alloc((size_t)N * 4);
    u8*    Z       = (u8*)alloc((size_t)N * 128);        // fp8 gather buffer
    u16*   H       = (u16*)alloc((size_t)N * 128 * 2);   // bf16 agg output
    int*   row_off = (int*)alloc((size_t)(N + 1) * 4);
    int*   csr_src = (int*)alloc((size_t)E * 4);
    u32*   stage   = (u32*)alloc((size_t)E * 4);
    int*   bcnt    = (int*)alloc(256 * 4);
    int*   bbase   = (int*)alloc(260 * 4);
    int*   bkcur   = (int*)alloc(256 * 4);
    float* pooled  = (float*)alloc(64 * 128 * 4);
    u16*   Wt1     = (u16*)alloc(128 * 128 * 2);
    u16*   Wt2     = (u16*)alloc(128 * 128 * 2);

    k_init<<<1 + (64 * 128 + 255) / 256, 256, 0, stream>>>(bcnt, bkcur, pooled);
    k_bhist<<<(E + BH_CHUNK - 1) / BH_CHUNK, 256, 0, stream>>>(dst, E, bcnt, nbuck);
    k_bscan<<<1, 256, 0, stream>>>(bcnt, bbase, row_off, nbuck, N, E);
    k_wt<<<2, 256, 0, stream>>>(W1, W2, Wt1, Wt2);
    k_bucketA<<<(E + EPB - 1) / EPB, 256, 0, stream>>>(src, dst, E, bbase, bkcur, stage, nbuck);
    k_bucketB<<<nbuck, 256, 0, stream>>>(stage, bbase, csr_src, row_off, dinv, N);

    k_gemm_mfma<float><<<(N + 127) / 128, 256, 0, stream>>>(x, Wt1, dinv, Z, N);
    k_agg<<<(N + 7) / 8, 256, 0, stream>>>(Z, dinv, row_off, csr_src, b1, H, N, 1);
    k_gemm_mfma<u16><<<(N + 127) / 128, 256, 0, stream>>>(H, Wt2, dinv, Z, N);
    k_agg<<<(N + 7) / 8, 256, 0, stream>>>(Z, dinv, row_off, csr_src, b2, H, N, 0);
    k_pool_partial<<<2048, 64, 0, stream>>>(H, batch, N, pooled);
    k_pool_final<<<64, 128, 0, stream>>>(batch, N, pooled);
    k_mlp<<<64, 64, 0, stream>>>(pooled, Wl1, bl1, Wl2, bl2, out);
}